// Round 15
// baseline (112.556 us; speedup 1.0000x reference)
//
#include <hip/hip_runtime.h>

typedef __attribute__((ext_vector_type(8))) __bf16 bf16x8;
typedef __attribute__((ext_vector_type(4))) float f32x4;

#define GRID_W 512
#define GRID_H 512
#define HW (GRID_W * GRID_H)      // 262144
#define NPTS 250000
#define NB 2
#define NCELLS (NB * HW)          // 524288
#define SCAT_BLOCKS ((NB * NPTS + 255) / 256)   // 1954

// Voxel index matching XLA: divide-by-const -> multiply-by-reciprocal;
// 1/0.2f == 5.0f exactly. _rn blocks contraction.
__device__ __forceinline__ void cell_of(float x, float y, int& xi, int& yi) {
    xi = (int)__fmul_rn(__fadd_rn(x, 51.2f), 5.0f);
    yi = (int)__fmul_rn(__fadd_rn(y, 51.2f), 5.0f);
}

// ---------- kernel 1: scatter (blocks < SCAT_BLOCKS) + weight prep ----------
// W2/W3 folded+split into bf16 hi/lo IN MFMA B-FRAGMENT ORDER:
//   elem e = ((nt*8 + g)*16 + n)*8 + j  <->  W[k = g*8+j][nglob = nt*16+n]
__global__ __launch_bounds__(256) void k_scat_prep(
    const float* __restrict__ pts, int* __restrict__ win,
    const float* __restrict__ W1, const float* __restrict__ b1,
    const float* __restrict__ g1, const float* __restrict__ be1,
    const float* __restrict__ m1, const float* __restrict__ v1,
    const float* __restrict__ W2, const float* __restrict__ b2,
    const float* __restrict__ g2, const float* __restrict__ be2,
    const float* __restrict__ m2, const float* __restrict__ v2,
    const float* __restrict__ W3, const float* __restrict__ b3,
    float* __restrict__ w1f, float* __restrict__ bb1,
    float* __restrict__ bb2, float* __restrict__ b3f,
    __bf16* __restrict__ w2hi, __bf16* __restrict__ w2lo,
    __bf16* __restrict__ w3hi, __bf16* __restrict__ w3lo)
{
    if (blockIdx.x < SCAT_BLOCKS) {
        int gid = blockIdx.x * 256 + threadIdx.x;
        if (gid >= NB * NPTS) return;
        int b = gid / NPTS;
        int i = gid - b * NPTS;
        const float* p = pts + (size_t)gid * 5;
        int xi, yi;
        cell_of(p[0], p[1], xi, yi);
        if (xi >= 0 && xi < GRID_W && yi >= 0 && yi < GRID_H) {
            atomicMax(&win[b * HW + yi * GRID_W + xi], i);
        }
        return;
    }
    int gid = (blockIdx.x - SCAT_BLOCKS) * 256 + threadIdx.x;
    if (gid < 64) {
        int t = gid;
        float s1 = g1[t] / sqrtf(v1[t] + 1e-5f);
        bb1[t] = (b1[t] - m1[t]) * s1 + be1[t];
        float s2 = g2[t] / sqrtf(v2[t] + 1e-5f);
        bb2[t] = (b2[t] - m2[t]) * s2 + be2[t];
    } else if (gid < 192) {
        b3f[gid - 64] = b3[gid - 64];
    } else if (gid < 704) {
        int e = gid - 192;                        // w1f[k*64+j] = W1*s1[j]
        int j = e & 63;
        float s1 = g1[j] / sqrtf(v1[j] + 1e-5f);
        w1f[e] = W1[e] * s1;
    } else if (gid < 4800) {
        int e = gid - 704;                        // W2 frags (s2 folded)
        int j = e & 7, n = (e >> 3) & 15, g = (e >> 7) & 7, nt = e >> 10;
        int k = g * 8 + j, ng = nt * 16 + n;
        float s2 = g2[ng] / sqrtf(v2[ng] + 1e-5f);
        float wf = W2[k * 64 + ng] * s2;
        __bf16 hi = (__bf16)wf;
        w2hi[e] = hi;
        w2lo[e] = (__bf16)(wf - (float)hi);
    } else if (gid < 12992) {
        int e = gid - 4800;                       // W3 frags
        int j = e & 7, n = (e >> 3) & 15, g = (e >> 7) & 7, nt = e >> 10;
        int k = g * 8 + j, ng = nt * 16 + n;
        float wf = W3[k * 128 + ng];
        __bf16 hi = (__bf16)wf;
        w3hi[e] = hi;
        w3lo[e] = (__bf16)(wf - (float)hi);
    }
}

// -------------------- kernel 2: MFMA MLP, two-tile pipelined ----------------
// 512 cells/block (2 tiles of 256), weights staged once per block. Both
// tiles' win loads + point gathers issue at entry (2x outstanding latency).
// Masks via intra-wave __ballot (no LDS). One __syncthreads total; all
// hot-loop LDS wave-private (sAhi[wv], sT[wv]); barrier-free stores.
__global__ __launch_bounds__(256, 3) void k_mlp(
    const float* __restrict__ pts, const int* __restrict__ win,
    const float* __restrict__ w1f, const float* __restrict__ bb1,
    const float* __restrict__ bb2, const float* __restrict__ b3f,
    const __bf16* __restrict__ w2hi, const __bf16* __restrict__ w2lo,
    const __bf16* __restrict__ w3hi, const __bf16* __restrict__ w3lo,
    float* __restrict__ out)
{
    __shared__ float sW1f[512];
    __shared__ float sBB1[64], sBB2[64], sB3[128];
    __shared__ __bf16 sAhi[4][4096];   // per-wave 64 cells x 64 k, frag order
    __shared__ float sT[4][16 * 68];   // per-wave [ch][68]: 64 cells + pad

    const int t = threadIdx.x;
    const int wv = t >> 6;
    const int lane = t & 63;

    const int bI = blockIdx.x >> 9;                  // batch (512 blocks each)
    const int cellBase = (blockIdx.x & 511) * 512;
    const int gcell = bI * HW + cellBase + t;

    // both tiles' winners + ballots + point gathers up front
    int w0 = win[gcell];
    int w1 = win[gcell + 256];
    unsigned long long mb[2];
    mb[0] = __ballot(w0 >= 0);
    mb[1] = __ballot(w1 >= 0);
    float P[2][5];
#pragma unroll
    for (int tl = 0; tl < 2; ++tl)
#pragma unroll
        for (int c = 0; c < 5; ++c) P[tl][c] = 0.0f;
    if (w0 >= 0) {
        const float* p = pts + ((size_t)bI * NPTS + w0) * 5;
        P[0][0] = p[0]; P[0][1] = p[1]; P[0][2] = p[2]; P[0][3] = p[3]; P[0][4] = p[4];
    }
    if (w1 >= 0) {
        const float* p = pts + ((size_t)bI * NPTS + w1) * 5;
        P[1][0] = p[0]; P[1][1] = p[1]; P[1][2] = p[2]; P[1][3] = p[3]; P[1][4] = p[4];
    }

    if (t < 128)      ((float4*)sW1f)[t]       = ((const float4*)w1f)[t];
    else if (t < 144) ((float4*)sBB1)[t - 128] = ((const float4*)bb1)[t - 128];
    else if (t < 160) ((float4*)sBB2)[t - 144] = ((const float4*)bb2)[t - 144];
    else if (t < 192) ((float4*)sB3)[t - 160]  = ((const float4*)b3f)[t - 160];
    __syncthreads();                       // the ONLY block barrier

    const int g = lane >> 4;               // 0..3
    const int ch = lane & 15;
    float* sTw = sT[wv];

#pragma unroll
    for (int tl = 0; tl < 2; ++tl) {
        // ---- layer 1: 8 -> 64, f32 ----
        float a8[8];
        a8[0] = P[tl][0]; a8[1] = P[tl][1]; a8[2] = P[tl][2];
        a8[3] = P[tl][3]; a8[4] = P[tl][4];
        {
            int xi, yi;
            cell_of(a8[0], a8[1], xi, yi);
            float xc = __fadd_rn(__fmul_rn((float)xi, 0.2f), -51.1f);
            float yc = __fadd_rn(__fmul_rn((float)yi, 0.2f), -51.1f);
            a8[5] = __fadd_rn(a8[0], -xc);
            a8[6] = __fadd_rn(a8[1], -yc);
            a8[7] = 0.0f;
        }
        float h1[64];
#pragma unroll
        for (int j4 = 0; j4 < 16; ++j4) {
            float4 acc = ((const float4*)sBB1)[j4];
#pragma unroll
            for (int k = 0; k < 8; ++k) {
                float4 wq = ((const float4*)sW1f)[k * 16 + j4];
                acc.x = fmaf(a8[k], wq.x, acc.x);
                acc.y = fmaf(a8[k], wq.y, acc.y);
                acc.z = fmaf(a8[k], wq.z, acc.z);
                acc.w = fmaf(a8[k], wq.w, acc.w);
            }
            h1[j4 * 4 + 0] = fmaxf(acc.x, 0.0f);
            h1[j4 * 4 + 1] = fmaxf(acc.y, 0.0f);
            h1[j4 * 4 + 2] = fmaxf(acc.z, 0.0f);
            h1[j4 * 4 + 3] = fmaxf(acc.w, 0.0f);
        }

        // h1 -> bf16 hi into A-fragment order
        {
            int abase = g * 1024 + ch * 8;
#pragma unroll
            for (int gg = 0; gg < 8; ++gg) {
                bf16x8 hi8;
#pragma unroll
                for (int j = 0; j < 8; ++j)
                    hi8[j] = (__bf16)h1[gg * 8 + j];
                *(bf16x8*)&sAhi[wv][abase + gg * 128] = hi8;
            }
        }

        // ---- A-fragments for layer 2 ----
        bf16x8 Ahi[4][2];
#pragma unroll
        for (int mt = 0; mt < 4; ++mt)
#pragma unroll
            for (int ks = 0; ks < 2; ++ks)
                Ahi[mt][ks] = *(const bf16x8*)&sAhi[wv][mt * 1024 + ks * 512 + lane * 8];

        // ---- layer 2: 64 -> 64 (2-term MFMA) ----
#pragma unroll
        for (int nt = 0; nt < 4; ++nt) {
            bf16x8 Bhi[2], Blo[2];
#pragma unroll
            for (int ks = 0; ks < 2; ++ks) {
                int off = nt * 1024 + ks * 512 + lane * 8;
                Bhi[ks] = *(const bf16x8*)&w2hi[off];
                Blo[ks] = *(const bf16x8*)&w2lo[off];
            }
            f32x4 zero = {0.f, 0.f, 0.f, 0.f};
            f32x4 acc[4] = {zero, zero, zero, zero};
#pragma unroll
            for (int mt = 0; mt < 4; ++mt)
#pragma unroll
                for (int ks = 0; ks < 2; ++ks) {
                    acc[mt] = __builtin_amdgcn_mfma_f32_16x16x32_bf16(Ahi[mt][ks], Bhi[ks], acc[mt], 0, 0, 0);
                    acc[mt] = __builtin_amdgcn_mfma_f32_16x16x32_bf16(Ahi[mt][ks], Blo[ks], acc[mt], 0, 0, 0);
                }
            float bb2l = sBB2[nt * 16 + ch];
            int gg = nt * 2 + (ch >> 3);
            int jj = lane & 7;
#pragma unroll
            for (int mt = 0; mt < 4; ++mt)
#pragma unroll
                for (int r = 0; r < 4; ++r) {
                    float h = fmaxf(acc[mt][r] + bb2l, 0.0f);
                    int off = mt * 1024 + gg * 128 + (g * 4 + r) * 8 + jj;
                    sAhi[wv][off] = (__bf16)h;
                }
        }

        // ---- A-fragments for layer 3 (h2) ----
#pragma unroll
        for (int mt = 0; mt < 4; ++mt)
#pragma unroll
            for (int ks = 0; ks < 2; ++ks)
                Ahi[mt][ks] = *(const bf16x8*)&sAhi[wv][mt * 1024 + ks * 512 + lane * 8];

        // masks from ballot: cell-in-wave = mt*16 + g*4 + r
        float4 mk[4];
#pragma unroll
        for (int mt = 0; mt < 4; ++mt) {
            int base = mt * 16 + g * 4;
            mk[mt].x = ((mb[tl] >> (base + 0)) & 1ull) ? 1.0f : 0.0f;
            mk[mt].y = ((mb[tl] >> (base + 1)) & 1ull) ? 1.0f : 0.0f;
            mk[mt].z = ((mb[tl] >> (base + 2)) & 1ull) ? 1.0f : 0.0f;
            mk[mt].w = ((mb[tl] >> (base + 3)) & 1ull) ? 1.0f : 0.0f;
        }

        // ---- layer 3: 64 -> 128, wave-private transpose, barrier-free stores ----
        float* outW = out + (size_t)bI * 128 * HW + cellBase + tl * 256 + wv * 64;
#pragma unroll
        for (int nt = 0; nt < 8; ++nt) {
            bf16x8 Bhi[2], Blo[2];
#pragma unroll
            for (int ks = 0; ks < 2; ++ks) {
                int off = nt * 1024 + ks * 512 + lane * 8;
                Bhi[ks] = *(const bf16x8*)&w3hi[off];
                Blo[ks] = *(const bf16x8*)&w3lo[off];
            }
            f32x4 zero = {0.f, 0.f, 0.f, 0.f};
            f32x4 acc[4] = {zero, zero, zero, zero};
#pragma unroll
            for (int mt = 0; mt < 4; ++mt)
#pragma unroll
                for (int ks = 0; ks < 2; ++ks) {
                    acc[mt] = __builtin_amdgcn_mfma_f32_16x16x32_bf16(Ahi[mt][ks], Bhi[ks], acc[mt], 0, 0, 0);
                    acc[mt] = __builtin_amdgcn_mfma_f32_16x16x32_bf16(Ahi[mt][ks], Blo[ks], acc[mt], 0, 0, 0);
                }
            float b3l = sB3[nt * 16 + ch];

            // stage into wave-private sT[ch][cell]
#pragma unroll
            for (int mt = 0; mt < 4; ++mt) {
                f32x4 o;
                o[0] = (acc[mt][0] + b3l) * mk[mt].x;
                o[1] = (acc[mt][1] + b3l) * mk[mt].y;
                o[2] = (acc[mt][2] + b3l) * mk[mt].z;
                o[3] = (acc[mt][3] + b3l) * mk[mt].w;
                *(f32x4*)&sTw[ch * 68 + mt * 16 + g * 4] = o;
            }
            // read transposed: 4 channels per instr, 16 lanes x 16B = 256 B/channel
#pragma unroll
            for (int j = 0; j < 4; ++j) {
                int chl = j * 4 + g;
                f32x4 v = *(const f32x4*)&sTw[chl * 68 + ch * 4];
                *(f32x4*)(outW + (size_t)(nt * 16 + chl) * HW + ch * 4) = v;
            }
        }
    }
}

extern "C" void kernel_launch(void* const* d_in, const int* in_sizes, int n_in,
                              void* d_out, int out_size, void* d_ws, size_t ws_size,
                              hipStream_t stream) {
    const float* pts = (const float*)d_in[0];
    const float* W1  = (const float*)d_in[1];
    const float* b1  = (const float*)d_in[2];
    const float* g1  = (const float*)d_in[3];
    const float* be1 = (const float*)d_in[4];
    const float* m1  = (const float*)d_in[5];
    const float* v1  = (const float*)d_in[6];
    const float* W2  = (const float*)d_in[7];
    const float* b2  = (const float*)d_in[8];
    const float* g2  = (const float*)d_in[9];
    const float* be2 = (const float*)d_in[10];
    const float* m2  = (const float*)d_in[11];
    const float* v2  = (const float*)d_in[12];
    const float* W3  = (const float*)d_in[13];
    const float* b3  = (const float*)d_in[14];
    float* out = (float*)d_out;

    char* wsb = (char*)d_ws;
    int*    win  = (int*)wsb;                         // 2 MiB
    float*  w1f  = (float*)(wsb + 2097152);           // 2048 B
    float*  bb1  = (float*)(wsb + 2097152 + 2048);    // 256 B
    float*  bb2  = (float*)(wsb + 2097152 + 2304);    // 256 B
    float*  b3f  = (float*)(wsb + 2097152 + 2560);    // 512 B
    __bf16* w2hi = (__bf16*)(wsb + 2097152 + 3072);   // 8 KiB
    __bf16* w2lo = w2hi + 4096;                       // 8 KiB
    __bf16* w3hi = w2lo + 4096;                       // 16 KiB
    __bf16* w3lo = w3hi + 8192;                       // 16 KiB

    // win = -1 everywhere: every byte 0xFF (capture-safe async memset)
    hipMemsetAsync(win, 0xFF, (size_t)NCELLS * sizeof(int), stream);
    k_scat_prep<<<SCAT_BLOCKS + 51, 256, 0, stream>>>(pts, win,
        W1, b1, g1, be1, m1, v1,
        W2, b2, g2, be2, m2, v2, W3, b3,
        w1f, bb1, bb2, b3f, w2hi, w2lo, w3hi, w3lo);
    k_mlp<<<NCELLS / 512, 256, 0, stream>>>(pts, win,
        w1f, bb1, bb2, b3f, w2hi, w2lo, w3hi, w3lo, out);
}

// Round 17
// 83.403 us; speedup vs baseline: 1.3495x; 1.3495x over previous
//
#include <hip/hip_runtime.h>

typedef __attribute__((ext_vector_type(8))) __bf16 bf16x8;
typedef __attribute__((ext_vector_type(4))) float f32x4;

#define GRID_W 512
#define GRID_H 512
#define HW (GRID_W * GRID_H)      // 262144
#define NPTS 250000
#define NB 2
#define NCELLS (NB * HW)          // 524288
#define SCAT_BLOCKS ((NB * NPTS + 255) / 256)   // 1954

// Voxel index matching XLA: divide-by-const -> multiply-by-reciprocal;
// 1/0.2f == 5.0f exactly. _rn blocks contraction.
__device__ __forceinline__ void cell_of(float x, float y, int& xi, int& yi) {
    xi = (int)__fmul_rn(__fadd_rn(x, 51.2f), 5.0f);
    yi = (int)__fmul_rn(__fadd_rn(y, 51.2f), 5.0f);
}

// ---------- kernel 1: scatter (blocks < SCAT_BLOCKS) + weight prep ----------
// W2/W3 folded+split into bf16 hi/lo IN MFMA B-FRAGMENT ORDER:
//   elem e = ((nt*8 + g)*16 + n)*8 + j  <->  W[k = g*8+j][nglob = nt*16+n]
__global__ __launch_bounds__(256) void k_scat_prep(
    const float* __restrict__ pts, int* __restrict__ win,
    const float* __restrict__ W1, const float* __restrict__ b1,
    const float* __restrict__ g1, const float* __restrict__ be1,
    const float* __restrict__ m1, const float* __restrict__ v1,
    const float* __restrict__ W2, const float* __restrict__ b2,
    const float* __restrict__ g2, const float* __restrict__ be2,
    const float* __restrict__ m2, const float* __restrict__ v2,
    const float* __restrict__ W3, const float* __restrict__ b3,
    float* __restrict__ w1f, float* __restrict__ bb1,
    float* __restrict__ bb2, float* __restrict__ b3f,
    __bf16* __restrict__ w2hi, __bf16* __restrict__ w2lo,
    __bf16* __restrict__ w3hi, __bf16* __restrict__ w3lo)
{
    if (blockIdx.x < SCAT_BLOCKS) {
        int gid = blockIdx.x * 256 + threadIdx.x;
        if (gid >= NB * NPTS) return;
        int b = gid / NPTS;
        int i = gid - b * NPTS;
        const float* p = pts + (size_t)gid * 5;
        int xi, yi;
        cell_of(p[0], p[1], xi, yi);
        if (xi >= 0 && xi < GRID_W && yi >= 0 && yi < GRID_H) {
            atomicMax(&win[b * HW + yi * GRID_W + xi], i);
        }
        return;
    }
    int gid = (blockIdx.x - SCAT_BLOCKS) * 256 + threadIdx.x;
    if (gid < 64) {
        int t = gid;
        float s1 = g1[t] / sqrtf(v1[t] + 1e-5f);
        bb1[t] = (b1[t] - m1[t]) * s1 + be1[t];
        float s2 = g2[t] / sqrtf(v2[t] + 1e-5f);
        bb2[t] = (b2[t] - m2[t]) * s2 + be2[t];
    } else if (gid < 192) {
        b3f[gid - 64] = b3[gid - 64];
    } else if (gid < 704) {
        int e = gid - 192;                        // w1f[k*64+j] = W1*s1[j]
        int j = e & 63;
        float s1 = g1[j] / sqrtf(v1[j] + 1e-5f);
        w1f[e] = W1[e] * s1;
    } else if (gid < 4800) {
        int e = gid - 704;                        // W2 frags (s2 folded)
        int j = e & 7, n = (e >> 3) & 15, g = (e >> 7) & 7, nt = e >> 10;
        int k = g * 8 + j, ng = nt * 16 + n;
        float s2 = g2[ng] / sqrtf(v2[ng] + 1e-5f);
        float wf = W2[k * 64 + ng] * s2;
        __bf16 hi = (__bf16)wf;
        w2hi[e] = hi;
        w2lo[e] = (__bf16)(wf - (float)hi);
    } else if (gid < 12992) {
        int e = gid - 4800;                       // W3 frags
        int j = e & 7, n = (e >> 3) & 15, g = (e >> 7) & 7, nt = e >> 10;
        int k = g * 8 + j, ng = nt * 16 + n;
        float wf = W3[k * 128 + ng];
        __bf16 hi = (__bf16)wf;
        w3hi[e] = hi;
        w3lo[e] = (__bf16)(wf - (float)hi);
    }
}

// -------------------- kernel 2: MFMA MLP, high-occupancy ----------------
// Round-14 structure (single tile, barrier-free after one staging barrier,
// wave-private LDS) with two LDS cuts:
//   - masks via intra-wave __ballot (sMask LDS removed),
//   - store-transpose buffer ALIASED onto sAhi[wv] (dead after layer-3
//     A-frag reads; same-wave LDS ops complete in order -> no barrier).
// LDS ~35.8 KB -> 4 blocks/CU = 16 waves/CU; launch_bounds(256,4) caps
// VGPR at 128.
__global__ __launch_bounds__(256, 4) void k_mlp(
    const float* __restrict__ pts, const int* __restrict__ win,
    const float* __restrict__ w1f, const float* __restrict__ bb1,
    const float* __restrict__ bb2, const float* __restrict__ b3f,
    const __bf16* __restrict__ w2hi, const __bf16* __restrict__ w2lo,
    const __bf16* __restrict__ w3hi, const __bf16* __restrict__ w3lo,
    float* __restrict__ out)
{
    __shared__ float sW1f[512];
    __shared__ float sBB1[64], sBB2[64], sB3[128];
    __shared__ __bf16 sAhi[4][4096];   // per-wave 64 cells x 64 k, frag order
                                       // (reused as the store-transpose buf)

    const int t = threadIdx.x;
    const int wv = t >> 6;
    const int lane = t & 63;

    const int bI = blockIdx.x >> 10;                 // batch (1024 blocks each)
    const int cellBase = (blockIdx.x & 1023) * 256;
    const int gcell = bI * HW + cellBase + t;

    int w = win[gcell];
    unsigned long long mb = __ballot(w >= 0);

    // early point gather (hides under staging + layer 1)
    float px = 0.f, py = 0.f, pz = 0.f, pin = 0.f, ptm = 0.f;
    if (w >= 0) {
        const float* p = pts + ((size_t)bI * NPTS + w) * 5;
        px = p[0]; py = p[1]; pz = p[2]; pin = p[3]; ptm = p[4];
    }

    if (t < 128)      ((float4*)sW1f)[t]       = ((const float4*)w1f)[t];
    else if (t < 144) ((float4*)sBB1)[t - 128] = ((const float4*)bb1)[t - 128];
    else if (t < 160) ((float4*)sBB2)[t - 144] = ((const float4*)bb2)[t - 144];
    else if (t < 192) ((float4*)sB3)[t - 160]  = ((const float4*)b3f)[t - 160];
    __syncthreads();                       // the ONLY block barrier

    // ---- layer 1: 8 -> 64, f32 (garbage for empty cells; masked at store) ----
    float a8[8];
    a8[0] = px; a8[1] = py; a8[2] = pz; a8[3] = pin; a8[4] = ptm;
    {
        int xi, yi;
        cell_of(px, py, xi, yi);
        float xc = __fadd_rn(__fmul_rn((float)xi, 0.2f), -51.1f);
        float yc = __fadd_rn(__fmul_rn((float)yi, 0.2f), -51.1f);
        a8[5] = __fadd_rn(px, -xc);
        a8[6] = __fadd_rn(py, -yc);
        a8[7] = 0.0f;
    }
    float h1[64];
#pragma unroll
    for (int j4 = 0; j4 < 16; ++j4) {
        float4 acc = ((const float4*)sBB1)[j4];
#pragma unroll
        for (int k = 0; k < 8; ++k) {
            float4 wq = ((const float4*)sW1f)[k * 16 + j4];
            acc.x = fmaf(a8[k], wq.x, acc.x);
            acc.y = fmaf(a8[k], wq.y, acc.y);
            acc.z = fmaf(a8[k], wq.z, acc.z);
            acc.w = fmaf(a8[k], wq.w, acc.w);
        }
        h1[j4 * 4 + 0] = fmaxf(acc.x, 0.0f);
        h1[j4 * 4 + 1] = fmaxf(acc.y, 0.0f);
        h1[j4 * 4 + 2] = fmaxf(acc.z, 0.0f);
        h1[j4 * 4 + 3] = fmaxf(acc.w, 0.0f);
    }

    // h1 -> bf16 hi into A-fragment order:
    // off(mt,g,m,j) = mt*1024 + g*128 + m*8 + j   (cell-in-wave = mt*16+m)
    {
        int abase = (lane >> 4) * 1024 + (lane & 15) * 8;
#pragma unroll
        for (int g = 0; g < 8; ++g) {
            bf16x8 hi8;
#pragma unroll
            for (int j = 0; j < 8; ++j)
                hi8[j] = (__bf16)h1[g * 8 + j];
            *(bf16x8*)&sAhi[wv][abase + g * 128] = hi8;
        }
    }

    // ---- A-fragments for layer 2 (wave-private LDS) ----
    bf16x8 Ahi[4][2];
#pragma unroll
    for (int mt = 0; mt < 4; ++mt)
#pragma unroll
        for (int ks = 0; ks < 2; ++ks)
            Ahi[mt][ks] = *(const bf16x8*)&sAhi[wv][mt * 1024 + ks * 512 + lane * 8];

    // ---- layer 2: 64 -> 64 (2-term MFMA) ----
#pragma unroll
    for (int nt = 0; nt < 4; ++nt) {
        bf16x8 Bhi[2], Blo[2];
#pragma unroll
        for (int ks = 0; ks < 2; ++ks) {
            int off = nt * 1024 + ks * 512 + lane * 8;
            Bhi[ks] = *(const bf16x8*)&w2hi[off];
            Blo[ks] = *(const bf16x8*)&w2lo[off];
        }
        f32x4 zero = {0.f, 0.f, 0.f, 0.f};
        f32x4 acc[4] = {zero, zero, zero, zero};
#pragma unroll
        for (int mt = 0; mt < 4; ++mt)
#pragma unroll
            for (int ks = 0; ks < 2; ++ks) {
                acc[mt] = __builtin_amdgcn_mfma_f32_16x16x32_bf16(Ahi[mt][ks], Bhi[ks], acc[mt], 0, 0, 0);
                acc[mt] = __builtin_amdgcn_mfma_f32_16x16x32_bf16(Ahi[mt][ks], Blo[ks], acc[mt], 0, 0, 0);
            }
        float bb2l = sBB2[nt * 16 + (lane & 15)];
        int gg = nt * 2 + ((lane & 15) >> 3);
        int jj = lane & 7;
#pragma unroll
        for (int mt = 0; mt < 4; ++mt)
#pragma unroll
            for (int r = 0; r < 4; ++r) {
                float h = fmaxf(acc[mt][r] + bb2l, 0.0f);
                int off = mt * 1024 + gg * 128 + ((lane >> 4) * 4 + r) * 8 + jj;
                sAhi[wv][off] = (__bf16)h;
            }
    }

    // ---- A-fragments for layer 3 (h2); sAhi[wv] is DEAD after these reads ----
#pragma unroll
    for (int mt = 0; mt < 4; ++mt)
#pragma unroll
        for (int ks = 0; ks < 2; ++ks)
            Ahi[mt][ks] = *(const bf16x8*)&sAhi[wv][mt * 1024 + ks * 512 + lane * 8];

    // masks from ballot: cell-in-wave = mt*16 + (lane>>4)*4 + r
    float4 mk[4];
#pragma unroll
    for (int mt = 0; mt < 4; ++mt) {
        int base = mt * 16 + (lane >> 4) * 4;
        mk[mt].x = ((mb >> (base + 0)) & 1ull) ? 1.0f : 0.0f;
        mk[mt].y = ((mb >> (base + 1)) & 1ull) ? 1.0f : 0.0f;
        mk[mt].z = ((mb >> (base + 2)) & 1ull) ? 1.0f : 0.0f;
        mk[mt].w = ((mb >> (base + 3)) & 1ull) ? 1.0f : 0.0f;
    }

    // ---- layer 3: 64 -> 128, transpose via reused sAhi[wv], no barriers ----
    // Same-wave LDS ops complete in order: the 8 ds_read_b128 above return
    // data from before the ds_writes below. 16B alignment holds throughout.
    float* sTw = (float*)sAhi[wv];         // 16 ch x 68 floats = 4352 B of 8 KB
    float* outW = out + (size_t)bI * 128 * HW + cellBase + wv * 64;
    const int g = lane >> 4;               // 0..3 (cell sub-group)
    const int ch = lane & 15;              // channel within nt
#pragma unroll
    for (int nt = 0; nt < 8; ++nt) {
        bf16x8 Bhi[2], Blo[2];
#pragma unroll
        for (int ks = 0; ks < 2; ++ks) {
            int off = nt * 1024 + ks * 512 + lane * 8;
            Bhi[ks] = *(const bf16x8*)&w3hi[off];
            Blo[ks] = *(const bf16x8*)&w3lo[off];
        }
        f32x4 zero = {0.f, 0.f, 0.f, 0.f};
        f32x4 acc[4] = {zero, zero, zero, zero};
#pragma unroll
        for (int mt = 0; mt < 4; ++mt)
#pragma unroll
            for (int ks = 0; ks < 2; ++ks) {
                acc[mt] = __builtin_amdgcn_mfma_f32_16x16x32_bf16(Ahi[mt][ks], Bhi[ks], acc[mt], 0, 0, 0);
                acc[mt] = __builtin_amdgcn_mfma_f32_16x16x32_bf16(Ahi[mt][ks], Blo[ks], acc[mt], 0, 0, 0);
            }
        float b3l = sB3[nt * 16 + ch];

        // stage into wave-private sTw[ch][cell], cell = mt*16 + g*4 + r
#pragma unroll
        for (int mt = 0; mt < 4; ++mt) {
            f32x4 o;
            o[0] = (acc[mt][0] + b3l) * mk[mt].x;
            o[1] = (acc[mt][1] + b3l) * mk[mt].y;
            o[2] = (acc[mt][2] + b3l) * mk[mt].z;
            o[3] = (acc[mt][3] + b3l) * mk[mt].w;
            *(f32x4*)&sTw[ch * 68 + mt * 16 + g * 4] = o;
        }
        // read transposed: 4 channels per instr, 16 lanes x 16B = 256 B/channel
#pragma unroll
        for (int j = 0; j < 4; ++j) {
            int chl = j * 4 + g;
            f32x4 v = *(const f32x4*)&sTw[chl * 68 + ch * 4];
            *(f32x4*)(outW + (size_t)(nt * 16 + chl) * HW + ch * 4) = v;
        }
    }
}

extern "C" void kernel_launch(void* const* d_in, const int* in_sizes, int n_in,
                              void* d_out, int out_size, void* d_ws, size_t ws_size,
                              hipStream_t stream) {
    const float* pts = (const float*)d_in[0];
    const float* W1  = (const float*)d_in[1];
    const float* b1  = (const float*)d_in[2];
    const float* g1  = (const float*)d_in[3];
    const float* be1 = (const float*)d_in[4];
    const float* m1  = (const float*)d_in[5];
    const float* v1  = (const float*)d_in[6];
    const float* W2  = (const float*)d_in[7];
    const float* b2  = (const float*)d_in[8];
    const float* g2  = (const float*)d_in[9];
    const float* be2 = (const float*)d_in[10];
    const float* m2  = (const float*)d_in[11];
    const float* v2  = (const float*)d_in[12];
    const float* W3  = (const float*)d_in[13];
    const float* b3  = (const float*)d_in[14];
    float* out = (float*)d_out;

    char* wsb = (char*)d_ws;
    int*    win  = (int*)wsb;                         // 2 MiB
    float*  w1f  = (float*)(wsb + 2097152);           // 2048 B
    float*  bb1  = (float*)(wsb + 2097152 + 2048);    // 256 B
    float*  bb2  = (float*)(wsb + 2097152 + 2304);    // 256 B
    float*  b3f  = (float*)(wsb + 2097152 + 2560);    // 512 B
    __bf16* w2hi = (__bf16*)(wsb + 2097152 + 3072);   // 8 KiB
    __bf16* w2lo = w2hi + 4096;                       // 8 KiB
    __bf16* w3hi = w2lo + 4096;                       // 16 KiB
    __bf16* w3lo = w3hi + 8192;                       // 16 KiB

    // win = -1 everywhere: every byte 0xFF (capture-safe async memset)
    hipMemsetAsync(win, 0xFF, (size_t)NCELLS * sizeof(int), stream);
    k_scat_prep<<<SCAT_BLOCKS + 51, 256, 0, stream>>>(pts, win,
        W1, b1, g1, be1, m1, v1,
        W2, b2, g2, be2, m2, v2, W3, b3,
        w1f, bb1, bb2, b3f, w2hi, w2lo, w3hi, w3lo);
    k_mlp<<<NCELLS / 256, 256, 0, stream>>>(pts, win,
        w1f, bb1, bb2, b3f, w2hi, w2lo, w3hi, w3lo, out);
}